// Round 5
// baseline (297.185 us; speedup 1.0000x reference)
//
#include <hip/hip_runtime.h>
#include <hip/hip_bf16.h>

#define BATCH   16384
#define NUM_IN  4096
#define NUM_OUT 1024
#define NNZ     262144
#define BN_EPS  1e-3f

typedef __attribute__((ext_vector_type(8)))  short short8;
typedef __attribute__((ext_vector_type(4)))  float f32x4;
typedef __attribute__((ext_vector_type(4)))  unsigned int u32x4;

typedef __attribute__((address_space(3))) void        lds_void_t;
typedef const __attribute__((address_space(1))) void  g_void_t;

__device__ inline unsigned short f2bf(float f) {
    unsigned int u = __builtin_bit_cast(unsigned int, f);
    u += 0x7fffu + ((u >> 16) & 1u);
    return (unsigned short)(u >> 16);
}

// ---------------- kernel 1: zero W_t (fp32, transposed [NUM_OUT][NUM_IN]) ----
__global__ void k_zero(f32x4* __restrict__ p) {
    p[(size_t)blockIdx.x * 256 + threadIdx.x] = f32x4{0.f, 0.f, 0.f, 0.f};
}

// ---------------- kernel 2: scatter-add sparse values into W_t --------------
__global__ void k_scatter(const float* __restrict__ v, const int* __restrict__ r,
                          const int* __restrict__ c, float* __restrict__ wtf) {
    int i = blockIdx.x * 256 + threadIdx.x;
    atomicAdd(&wtf[(size_t)c[i] * NUM_IN + r[i]], v[i]);
}

// ---------------- kernel 3: fold BN scale into W (bf16) + bias_out ----------
__global__ void k_wprep(const float* __restrict__ wtf, const float* __restrict__ gamma,
                        const float* __restrict__ beta, const float* __restrict__ mean,
                        const float* __restrict__ var, unsigned short* __restrict__ wtb,
                        float* __restrict__ bias) {
    const int n = blockIdx.x;
    const int t = threadIdx.x;
    float acc = 0.f;
    for (int k = t; k < NUM_IN; k += 256) {
        float w = wtf[(size_t)n * NUM_IN + k];
        float s = gamma[k] * rsqrtf(var[k] + BN_EPS);
        wtb[(size_t)n * NUM_IN + k] = f2bf(w * s);
        acc += (beta[k] - mean[k] * s) * w;
    }
    #pragma unroll
    for (int o = 32; o; o >>= 1) acc += __shfl_down(acc, o, 64);
    __shared__ float red[4];
    if ((t & 63) == 0) red[t >> 6] = acc;
    __syncthreads();
    if (t == 0) bias[n] = red[0] + red[1] + red[2] + red[3];
}

// ---------------- kernel 4: bf16 MFMA GEMM (m201 8-phase template port) -----
// BM=BN=256, BK=64. 512 thr = 8 waves (2M x 4N), per-wave 128x64, 16x16x32 MFMA.
// 4 phases per K-tile: {ds_read issue (+stage issue) -> s_barrier -> lgkmcnt(0)
// -> 16 MFMA (setprio) -> s_barrier}. B via global_load_lds (pre-swizzled src,
// issued ph0, vmcnt(0) at ph3). A fp32 reg-staged: load ph0/ph1, perm+ds_write
// bf16 ph2/ph3. LDS rows 128 B, XOR swizzle (row&7)<<4. Double buffer 128 KB.
#define BM 256
#define BN 256
#define BK 64
#define NT (NUM_IN / BK)      /* 64 */
#define SLOT 65536            /* A 32 KB + B 32 KB */
#define BOFF 32768

__global__ __launch_bounds__(512, 2) void k_gemm(const float* __restrict__ x,
                                                 const unsigned short* __restrict__ wt,
                                                 const float* __restrict__ bias,
                                                 float* __restrict__ out) {
    __shared__ __align__(128) char lds[2 * SLOT];

    // XCD swizzle: 256 blocks (1/CU); XCD x gets 8 m-panels x all 4 n-tiles.
    const int bid = blockIdx.x;
    const int swz = (bid & 7) * 32 + (bid >> 3);
    const int m0 = (swz >> 2) * BM;
    const int n0 = (swz & 3) * BN;

    const int t    = threadIdx.x;
    const int lane = t & 63;
    const int wid  = t >> 6;
    const int wm   = wid >> 2;        // 0..1 -> 128-row strip
    const int wn   = wid & 3;         // 0..3 -> 64-col strip

    const char* xb = (const char*)x;
    const char* wb = (const char*)wt;

    // B staging (gload_lds): issue i covers rows i*64.., 8 thr/row (128 B)
    const int bg_r = t >> 3;
    const int bg_c = (t & 7) * 16;
    // A staging: thread t -> row t&255, k-half t>>8 (32 fp32 = 128 B)
    const int as_r = t & 255;
    const int as_h = t >> 8;
    const int as_s = (as_r & 7) << 4;

    auto stageB = [&](int kt, int slot) {
        #pragma unroll
        for (int i = 0; i < 4; ++i) {
            int row = i * 64 + bg_r;
            size_t src = (size_t)(n0 + row) * (NUM_IN * 2) + (size_t)kt * (BK * 2)
                       + (bg_c ^ ((row & 7) << 4));
            __builtin_amdgcn_global_load_lds((g_void_t*)(wb + src),
                (lds_void_t*)(lds + slot * SLOT + BOFF + i * 8192 + t * 16), 16, 0, 0);
        }
    };

    f32x4 rc0[4], rc1[4];
    auto loadA0 = [&](int kt) {
        size_t src = (size_t)(m0 + as_r) * (NUM_IN * 4) + (size_t)kt * (BK * 4)
                   + as_h * 128;
        #pragma unroll
        for (int j = 0; j < 4; ++j) rc0[j] = *(const f32x4*)(xb + src + j * 16);
    };
    auto loadA1 = [&](int kt) {
        size_t src = (size_t)(m0 + as_r) * (NUM_IN * 4) + (size_t)kt * (BK * 4)
                   + as_h * 128 + 64;
        #pragma unroll
        for (int j = 0; j < 4; ++j) rc1[j] = *(const f32x4*)(xb + src + j * 16);
    };
    // convert 16 fp32 -> 16 bf16, write 32 B to LDS (2x b128)
    auto writeA = [&](int slot, const f32x4* rc, int qb) {
        const unsigned int* f = (const unsigned int*)rc;
        u32x4 p0, p1;
        p0[0] = __builtin_amdgcn_perm(f[1],  f[0],  0x07060302u);
        p0[1] = __builtin_amdgcn_perm(f[3],  f[2],  0x07060302u);
        p0[2] = __builtin_amdgcn_perm(f[5],  f[4],  0x07060302u);
        p0[3] = __builtin_amdgcn_perm(f[7],  f[6],  0x07060302u);
        p1[0] = __builtin_amdgcn_perm(f[9],  f[8],  0x07060302u);
        p1[1] = __builtin_amdgcn_perm(f[11], f[10], 0x07060302u);
        p1[2] = __builtin_amdgcn_perm(f[13], f[12], 0x07060302u);
        p1[3] = __builtin_amdgcn_perm(f[15], f[14], 0x07060302u);
        char* dst = lds + slot * SLOT + as_r * 128;
        *(u32x4*)(dst + ((as_h * 64 + qb * 16)      ^ as_s)) = p0;
        *(u32x4*)(dst + ((as_h * 64 + qb * 16 + 16) ^ as_s)) = p1;
    };

    // fragment geometry (16x16x32): row = base + frag*16 + (lane&15),
    // k-byte = kk*64 + (lane>>4)*16, XOR (row&7)<<4
    const int fa_r = wm * 128 + (lane & 15);
    const int fb_r = wn * 64 + (lane & 15);
    const int f_kb = (lane >> 4) * 16;

    short8 bfr[4][2];
    auto readB = [&](int slot) {
        const char* B = lds + slot * SLOT + BOFF;
        #pragma unroll
        for (int j = 0; j < 4; ++j) {
            int row = fb_r + j * 16;
            int s = (row & 7) << 4;
            #pragma unroll
            for (int kk = 0; kk < 2; ++kk)
                bfr[j][kk] = *(const short8*)(B + row * 128 + ((kk * 64 + f_kb) ^ s));
        }
    };
    short8 af[2][2];
    auto readA2 = [&](int slot, int p) {
        const char* A = lds + slot * SLOT;
        #pragma unroll
        for (int mi = 0; mi < 2; ++mi) {
            int row = fa_r + (2 * p + mi) * 16;
            int s = (row & 7) << 4;
            #pragma unroll
            for (int kk = 0; kk < 2; ++kk)
                af[mi][kk] = *(const short8*)(A + row * 128 + ((kk * 64 + f_kb) ^ s));
        }
    };

    f32x4 acc[8][4] = {};
    auto mfma2 = [&](int p) {
        __builtin_amdgcn_s_setprio(1);
        #pragma unroll
        for (int kk = 0; kk < 2; ++kk)
            #pragma unroll
            for (int mi = 0; mi < 2; ++mi)
                #pragma unroll
                for (int n = 0; n < 4; ++n)
                    acc[2 * p + mi][n] = __builtin_amdgcn_mfma_f32_16x16x32_bf16(
                        af[mi][kk], bfr[n][kk], acc[2 * p + mi][n], 0, 0, 0);
        __builtin_amdgcn_s_setprio(0);
    };

    // ---------------- prologue: stage tile 0 into slot 0 --------------------
    stageB(0, 0);
    loadA0(0); loadA1(0);
    writeA(0, rc0, 0);
    writeA(0, rc1, 2);
    asm volatile("s_waitcnt vmcnt(0) lgkmcnt(0)" ::: "memory");
    __builtin_amdgcn_s_barrier();

    #pragma unroll 1
    for (int kt = 0; kt < NT; ++kt) {
        const int s = kt & 1;
        const bool st = (kt + 1) < NT;
        // ---- phase 0 ----
        if (st) { stageB(kt + 1, s ^ 1); loadA0(kt + 1); }
        readB(s); readA2(s, 0);
        __builtin_amdgcn_sched_barrier(0);
        __builtin_amdgcn_s_barrier();
        asm volatile("s_waitcnt lgkmcnt(0)" ::: "memory");
        __builtin_amdgcn_sched_barrier(0);
        mfma2(0);
        __builtin_amdgcn_sched_barrier(0);
        __builtin_amdgcn_s_barrier();
        // ---- phase 1 ----
        if (st) loadA1(kt + 1);
        readA2(s, 1);
        __builtin_amdgcn_sched_barrier(0);
        __builtin_amdgcn_s_barrier();
        asm volatile("s_waitcnt lgkmcnt(0)" ::: "memory");
        __builtin_amdgcn_sched_barrier(0);
        mfma2(1);
        __builtin_amdgcn_sched_barrier(0);
        __builtin_amdgcn_s_barrier();
        // ---- phase 2 ----
        if (st) writeA(s ^ 1, rc0, 0);
        readA2(s, 2);
        __builtin_amdgcn_sched_barrier(0);
        __builtin_amdgcn_s_barrier();
        asm volatile("s_waitcnt lgkmcnt(0)" ::: "memory");
        __builtin_amdgcn_sched_barrier(0);
        mfma2(2);
        __builtin_amdgcn_sched_barrier(0);
        __builtin_amdgcn_s_barrier();
        // ---- phase 3 ----
        if (st) writeA(s ^ 1, rc1, 2);
        readA2(s, 3);
        if (st) asm volatile("s_waitcnt vmcnt(0)" ::: "memory");  // B(kt+1) landed
        __builtin_amdgcn_sched_barrier(0);
        __builtin_amdgcn_s_barrier();
        asm volatile("s_waitcnt lgkmcnt(0)" ::: "memory");
        __builtin_amdgcn_sched_barrier(0);
        mfma2(3);
        __builtin_amdgcn_sched_barrier(0);
        __builtin_amdgcn_s_barrier();
    }

    // epilogue: D frag mapping col=lane&15, row=(lane>>4)*4+r
    float bj[4];
    #pragma unroll
    for (int n = 0; n < 4; ++n) bj[n] = bias[n0 + wn * 64 + n * 16 + (lane & 15)];
    const int mb = m0 + wm * 128 + (lane >> 4) * 4;
    const int nb = n0 + wn * 64 + (lane & 15);
    #pragma unroll
    for (int m = 0; m < 8; ++m)
        #pragma unroll
        for (int n = 0; n < 4; ++n)
            #pragma unroll
            for (int r = 0; r < 4; ++r)
                out[(size_t)(mb + m * 16 + r) * NUM_OUT + (nb + n * 16)] =
                    acc[m][n][r] + bj[n];
}

extern "C" void kernel_launch(void* const* d_in, const int* in_sizes, int n_in,
                              void* d_out, int out_size, void* d_ws, size_t ws_size,
                              hipStream_t stream) {
    const float* x     = (const float*)d_in[0];
    const float* spv   = (const float*)d_in[1];
    const float* gamma = (const float*)d_in[2];
    const float* beta  = (const float*)d_in[3];
    const float* mean  = (const float*)d_in[4];
    const float* var   = (const float*)d_in[5];
    const int*   rows  = (const int*)d_in[6];
    const int*   cols  = (const int*)d_in[7];
    float* out = (float*)d_out;

    // W_t fp32 scratch lives in d_out (dead before k_gemm overwrites it).
    float* wtf = (float*)d_out;
    unsigned short* wtb = (unsigned short*)d_ws;
    float* bias = (float*)((char*)d_ws + (size_t)NUM_IN * NUM_OUT * sizeof(unsigned short));

    hipLaunchKernelGGL(k_zero, dim3((NUM_IN * NUM_OUT / 4) / 256), dim3(256), 0, stream,
                       (f32x4*)wtf);
    hipLaunchKernelGGL(k_scatter, dim3(NNZ / 256), dim3(256), 0, stream,
                       spv, rows, cols, wtf);
    hipLaunchKernelGGL(k_wprep, dim3(NUM_OUT), dim3(256), 0, stream,
                       wtf, gamma, beta, mean, var, wtb, bias);
    hipLaunchKernelGGL(k_gemm, dim3((BATCH / BM) * (NUM_OUT / BN)), dim3(512), 0, stream,
                       x, wtb, bias, out);
}

// Round 6
// 206.269 us; speedup vs baseline: 1.4408x; 1.4408x over previous
//
#include <hip/hip_runtime.h>
#include <hip/hip_bf16.h>

#define BATCH   16384
#define NUM_IN  4096
#define NUM_OUT 1024
#define NNZ     262144
#define BN_EPS  1e-3f

typedef __attribute__((ext_vector_type(8)))  short short8;
typedef __attribute__((ext_vector_type(4)))  float f32x4;
typedef __attribute__((ext_vector_type(4)))  unsigned int u32x4;

typedef __attribute__((address_space(3))) void        lds_void_t;
typedef const __attribute__((address_space(1))) void  g_void_t;

__device__ inline unsigned short f2bf(float f) {
    unsigned int u = __builtin_bit_cast(unsigned int, f);
    u += 0x7fffu + ((u >> 16) & 1u);
    return (unsigned short)(u >> 16);
}

// ---------------- kernel 1: zero W_t (fp32, transposed [NUM_OUT][NUM_IN]) ----
__global__ void k_zero(f32x4* __restrict__ p) {
    p[(size_t)blockIdx.x * 256 + threadIdx.x] = f32x4{0.f, 0.f, 0.f, 0.f};
}

// ---------------- kernel 2: scatter-add sparse values into W_t --------------
__global__ void k_scatter(const float* __restrict__ v, const int* __restrict__ r,
                          const int* __restrict__ c, float* __restrict__ wtf) {
    int i = blockIdx.x * 256 + threadIdx.x;
    atomicAdd(&wtf[(size_t)c[i] * NUM_IN + r[i]], v[i]);
}

// ---------------- kernel 3: fold BN scale into W (bf16) + bias_out ----------
__global__ void k_wprep(const float* __restrict__ wtf, const float* __restrict__ gamma,
                        const float* __restrict__ beta, const float* __restrict__ mean,
                        const float* __restrict__ var, unsigned short* __restrict__ wtb,
                        float* __restrict__ bias) {
    const int n = blockIdx.x;
    const int t = threadIdx.x;
    float acc = 0.f;
    for (int k = t; k < NUM_IN; k += 256) {
        float w = wtf[(size_t)n * NUM_IN + k];
        float s = gamma[k] * rsqrtf(var[k] + BN_EPS);
        wtb[(size_t)n * NUM_IN + k] = f2bf(w * s);
        acc += (beta[k] - mean[k] * s) * w;
    }
    #pragma unroll
    for (int o = 32; o; o >>= 1) acc += __shfl_down(acc, o, 64);
    __shared__ float red[4];
    if ((t & 63) == 0) red[t >> 6] = acc;
    __syncthreads();
    if (t == 0) bias[n] = red[0] + red[1] + red[2] + red[3];
}

// ---------------- kernel 4: bf16 MFMA GEMM: out = x @ W'^T + bias -----------
// BM=BN=256, BK=32. 512 thr = 8 waves (2M x 4N), per-wave 128x64, 16x16x32.
// ALL staging via global_load_lds (A fp32 32KB, B bf16 16KB), ring-3 slots
// (144 KiB), prefetch distance 2, ONE counted vmcnt(6) per K-tile (T4).
// 2 phases/K-tile: {stage issue, frag-read issue, s_barrier, lgkmcnt(0),
// fp32->bf16 perm, 16 MFMA (setprio), s_barrier}. No ds_writes anywhere.
// Read swizzles: A rows 128B XOR (row&7)<<4; B rows 64B XOR ((row>>1)&3)<<4
// (both 2-way = free); sources pre-swizzled for linear gload_lds dest.
#define BM 256
#define BN 256
#define BK 32
#define NT (NUM_IN / BK)      /* 128 */
#define ASLOT 32768           /* 256 rows * 128 B (32 fp32) */
#define BSLOT 16384           /* 256 rows *  64 B (32 bf16) */
#define PSLOT 49152

__global__ __launch_bounds__(512, 2) void k_gemm(const float* __restrict__ x,
                                                 const unsigned short* __restrict__ wt,
                                                 const float* __restrict__ bias,
                                                 float* __restrict__ out) {
    __shared__ __align__(128) char lds[3 * PSLOT];   // 144 KiB

    // XCD swizzle: 256 blocks (1/CU); XCD x gets 8 m-panels x all 4 n-tiles.
    const int bid = blockIdx.x;
    const int swz = (bid & 7) * 32 + (bid >> 3);
    const int m0 = (swz >> 2) * BM;
    const int n0 = (swz & 3) * BN;

    const int t    = threadIdx.x;
    const int lane = t & 63;
    const int wid  = t >> 6;
    const int wm   = wid >> 2;        // 0..1 -> 128-row strip
    const int wn   = wid & 3;         // 0..3 -> 64-col strip

    const char* xb = (const char*)x;
    const char* wb = (const char*)wt;

    // A staging: 4 issues x 8KB (64 rows x 128 B); thread t -> row i*64+(t>>3),
    // 16B chunk (t&7); source chunk pre-XORed with (row&7).
    auto stageA = [&](int kt, int sl) {
        #pragma unroll
        for (int i = 0; i < 4; ++i) {
            int row = i * 64 + (t >> 3);
            size_t src = (size_t)(m0 + row) * (NUM_IN * 4) + (size_t)kt * (BK * 4)
                       + (((t & 7) ^ (row & 7)) * 16);
            __builtin_amdgcn_global_load_lds((g_void_t*)(xb + src),
                (lds_void_t*)(lds + sl * PSLOT + i * 8192 + t * 16), 16, 0, 0);
        }
    };
    // B staging: 2 issues x 8KB (128 rows x 64 B); chunk (t&3) ^ ((row>>1)&3).
    auto stageB = [&](int kt, int sl) {
        #pragma unroll
        for (int i = 0; i < 2; ++i) {
            int row = i * 128 + (t >> 2);
            size_t src = (size_t)(n0 + row) * (NUM_IN * 2) + (size_t)kt * (BK * 2)
                       + (((t & 3) ^ ((row >> 1) & 3)) * 16);
            __builtin_amdgcn_global_load_lds((g_void_t*)(wb + src),
                (lds_void_t*)(lds + sl * PSLOT + ASLOT + i * 8192 + t * 16), 16, 0, 0);
        }
    };

    // fragment geometry (16x16x32): row/col = base + 16*idx + (lane&15);
    // per-lane k: A 8 fp32 = 32 B at (lane>>4)*32; B 8 bf16 = 16 B at (lane>>4)*16
    const int fr   = lane & 15;
    const int a_k0 = (lane >> 4) * 32;
    const int b_k0 = (lane >> 4) * 16;

    f32x4 alo[4], ahi[4];
    short8 af[4], bfr[4];

    auto readB4 = [&](const char* B) {
        #pragma unroll
        for (int n = 0; n < 4; ++n) {
            int row = wn * 64 + n * 16 + fr;
            bfr[n] = *(const short8*)(B + row * 64 + (b_k0 ^ (((row >> 1) & 3) << 4)));
        }
    };
    auto readA4 = [&](const char* A, int mh) {
        #pragma unroll
        for (int m = 0; m < 4; ++m) {
            int row = wm * 128 + (mh + m) * 16 + fr;
            int s = (row & 7) << 4;
            alo[m] = *(const f32x4*)(A + row * 128 + (a_k0 ^ s));
            ahi[m] = *(const f32x4*)(A + row * 128 + ((a_k0 + 16) ^ s));
        }
    };
    auto convA = [&]() {
        #pragma unroll
        for (int m = 0; m < 4; ++m) {
            const unsigned int* f0 = (const unsigned int*)&alo[m];
            const unsigned int* f1 = (const unsigned int*)&ahi[m];
            u32x4 p;   // fp32 -> bf16 (RTZ), 1 v_perm per 2 elems
            p[0] = __builtin_amdgcn_perm(f0[1], f0[0], 0x07060302u);
            p[1] = __builtin_amdgcn_perm(f0[3], f0[2], 0x07060302u);
            p[2] = __builtin_amdgcn_perm(f1[1], f1[0], 0x07060302u);
            p[3] = __builtin_amdgcn_perm(f1[3], f1[2], 0x07060302u);
            af[m] = __builtin_bit_cast(short8, p);
        }
    };

    f32x4 acc[8][4] = {};
    auto mfma16 = [&](int mh) {
        __builtin_amdgcn_s_setprio(1);
        #pragma unroll
        for (int m = 0; m < 4; ++m)
            #pragma unroll
            for (int n = 0; n < 4; ++n)
                acc[mh + m][n] = __builtin_amdgcn_mfma_f32_16x16x32_bf16(
                    af[m], bfr[n], acc[mh + m][n], 0, 0, 0);
        __builtin_amdgcn_s_setprio(0);
    };

    // prologue: stage tiles 0,1; wait tile 0 (tile 1's 6 stay in flight)
    stageA(0, 0); stageB(0, 0);
    stageA(1, 1); stageB(1, 1);
    asm volatile("s_waitcnt vmcnt(6)" ::: "memory");
    __builtin_amdgcn_s_barrier();

    int cur = 0;
    #pragma unroll 1
    for (int kt = 0; kt < NT; ++kt) {
        const bool st = (kt + 2) < NT;
        const int stg = (cur >= 1) ? cur - 1 : cur + 2;   // (cur+2)%3
        const char* A = lds + cur * PSLOT;
        const char* B = A + ASLOT;
        // ---- phase 0: quadrant m0..3 ----
        if (st) stageA(kt + 2, stg);
        readB4(B);
        readA4(A, 0);
        __builtin_amdgcn_s_barrier();
        asm volatile("s_waitcnt lgkmcnt(0)" ::: "memory");
        __builtin_amdgcn_sched_barrier(0);
        convA();
        mfma16(0);
        __builtin_amdgcn_s_barrier();
        // ---- phase 1: quadrant m4..7 ----
        if (st) stageB(kt + 2, stg);
        readA4(A, 4);
        if (st) asm volatile("s_waitcnt vmcnt(6)" ::: "memory");  // kt+1 landed
        else    asm volatile("s_waitcnt vmcnt(0)" ::: "memory");
        __builtin_amdgcn_s_barrier();
        asm volatile("s_waitcnt lgkmcnt(0)" ::: "memory");
        __builtin_amdgcn_sched_barrier(0);
        convA();
        mfma16(4);
        __builtin_amdgcn_s_barrier();
        cur = (cur < 2) ? cur + 1 : 0;
    }

    // epilogue: D frag mapping col=lane&15, row=(lane>>4)*4+r
    float bj[4];
    #pragma unroll
    for (int n = 0; n < 4; ++n) bj[n] = bias[n0 + wn * 64 + n * 16 + fr];
    const int mb = m0 + wm * 128 + (lane >> 4) * 4;
    const int nb = n0 + wn * 64 + fr;
    #pragma unroll
    for (int m = 0; m < 8; ++m)
        #pragma unroll
        for (int n = 0; n < 4; ++n)
            #pragma unroll
            for (int r = 0; r < 4; ++r)
                out[(size_t)(mb + m * 16 + r) * NUM_OUT + (nb + n * 16)] =
                    acc[m][n][r] + bj[n];
}

extern "C" void kernel_launch(void* const* d_in, const int* in_sizes, int n_in,
                              void* d_out, int out_size, void* d_ws, size_t ws_size,
                              hipStream_t stream) {
    const float* x     = (const float*)d_in[0];
    const float* spv   = (const float*)d_in[1];
    const float* gamma = (const float*)d_in[2];
    const float* beta  = (const float*)d_in[3];
    const float* mean  = (const float*)d_in[4];
    const float* var   = (const float*)d_in[5];
    const int*   rows  = (const int*)d_in[6];
    const int*   cols  = (const int*)d_in[7];
    float* out = (float*)d_out;

    // W_t fp32 scratch lives in d_out (dead before k_gemm overwrites it).
    float* wtf = (float*)d_out;
    unsigned short* wtb = (unsigned short*)d_ws;
    float* bias = (float*)((char*)d_ws + (size_t)NUM_IN * NUM_OUT * sizeof(unsigned short));

    hipLaunchKernelGGL(k_zero, dim3((NUM_IN * NUM_OUT / 4) / 256), dim3(256), 0, stream,
                       (f32x4*)wtf);
    hipLaunchKernelGGL(k_scatter, dim3(NNZ / 256), dim3(256), 0, stream,
                       spv, rows, cols, wtf);
    hipLaunchKernelGGL(k_wprep, dim3(NUM_OUT), dim3(256), 0, stream,
                       wtf, gamma, beta, mean, var, wtb, bias);
    hipLaunchKernelGGL(k_gemm, dim3((BATCH / BM) * (NUM_OUT / BN)), dim3(512), 0, stream,
                       x, wtb, bias, out);
}